// Round 11
// baseline (327.181 us; speedup 1.0000x reference)
//
#include <hip/hip_runtime.h>
#include <hip/hip_bf16.h>
#include <math.h>

#define BB 1024
#define LL 32000
#define NCHUNK 16              // row chunks for prob partial sums
#define ROWS_PER_CHUNK (BB / NCHUNK)
#define NT 1024                // threads per block in fused k45
#define CAP 512                // max tied-u16-prefix group size (expect ~60)

// k3a rank tiling
#define RT_THREADS 256
#define RT_OWN 4                         // own keys per thread (in VGPRs)
#define RT_TI (RT_THREADS * RT_OWN)      // 1024 own elements per block
#define RT_TJ 500                        // j-tile size (4 KB LDS)
#define N_JTILE (LL / RT_TJ)             // 64
#define NPAD 32768
#define N_OWN_GRP (NPAD / RT_TI)         // 32
#define RT_NBLK (N_OWN_GRP * N_JTILE)    // 2048

constexpr float TINV = 0.25f;  // 1/T, T=4

// NOTE: all exponentials are computed WITHOUT max-stabilization. Inputs are
// N(0,1) logits (|x| < ~6), so e^x <= ~e^6 and e^{x/4} <= e^1.5 — no overflow
// or underflow risk in f32, and sums (<= ~5.3e4) are well within range.

typedef float vfloat4 __attribute__((ext_vector_type(4)));

__device__ __forceinline__ unsigned f2u(float x) {
  unsigned b = __float_as_uint(x);
  return (b & 0x80000000u) ? ~b : (b | 0x80000000u);
}
__device__ __forceinline__ float u2f(unsigned u) {
  unsigned b = (u & 0x80000000u) ? (u ^ 0x80000000u) : ~u;
  return __uint_as_float(b);
}

// K1: per-row student sums (branch-free). Pure 128 MB read-reduce.
__global__ __launch_bounds__(256) void k1_stats(
    const float* __restrict__ ls, const int* __restrict__ tgt,
    float* __restrict__ stats) {
  int r = blockIdx.x, tid = threadIdx.x;
  int lane = tid & 63, wv = tid >> 6;
  const float4* a4 = (const float4*)(ls + (size_t)r * LL);
  float s1 = 0.f, sT = 0.f;
  for (int i = tid; i < LL / 4; i += 256) {
    float4 a = a4[i];
    s1 += __expf(a.x) + __expf(a.y) + __expf(a.z) + __expf(a.w);
    sT += __expf(a.x * TINV) + __expf(a.y * TINV) +
          __expf(a.z * TINV) + __expf(a.w * TINV);
  }
  for (int o = 32; o > 0; o >>= 1) {
    s1 += __shfl_down(s1, o);
    sT += __shfl_down(sT, o);
  }
  __shared__ float wsum[8];
  if (lane == 0) { wsum[wv * 2] = s1; wsum[wv * 2 + 1] = sT; }
  __syncthreads();
  if (tid == 0) {
    float t1 = wsum[0] + wsum[2] + wsum[4] + wsum[6];
    float tT = wsum[1] + wsum[3] + wsum[5] + wsum[7];
    float lst = ls[(size_t)r * LL + tgt[r]];
    float* st = stats + r * 8;
    st[0] = t1; st[1] = tT; st[2] = lst; st[3] = 1.0f / t1;
  }
}

// K2a: partial column sums of T=1 softmax. Block (0,0) zeroes the k3a
// done-counter for this call.
__global__ __launch_bounds__(256) void k2a_prob_part(
    const float* __restrict__ ls, const float* __restrict__ stats,
    float* __restrict__ part, unsigned long long* __restrict__ aux) {
  if (blockIdx.x == 0 && blockIdx.y == 0 && threadIdx.x == 0) aux[0] = 0ull;
  int c = blockIdx.x * 256 + threadIdx.x;
  int r0 = blockIdx.y * ROWS_PER_CHUNK;
  float acc = 0.f;
#pragma unroll 8
  for (int rr = 0; rr < ROWS_PER_CHUNK; ++rr) {
    int r = r0 + rr;
    float rs = stats[r * 8 + 3];
    acc += __expf(ls[(size_t)r * LL + c]) * rs;
  }
  part[(size_t)blockIdx.y * LL + c] = acc;
}

// K2b: combine partials (deterministic) -> strict-total-order sort keys
// + zero the rank accumulator (aliased on part: column-exclusive, race-free).
__global__ __launch_bounds__(256) void k2b_prob(
    const float* __restrict__ part, unsigned long long* __restrict__ key,
    unsigned* __restrict__ rankc) {
  int c = blockIdx.x * 256 + threadIdx.x;
  float acc = 0.f;
#pragma unroll
  for (int j = 0; j < NCHUNK; ++j) acc += part[(size_t)j * LL + c];
  key[c] = ((unsigned long long)f2u(acc) << 32) | (unsigned)c;
  rankc[c] = 0u;
}

// K3a: tiled rank-by-counting (deterministic integer atomics into rankc),
// then the LAST block (device-scope counter) buckets quantized probs by
// rank/100 into LDS u64 bins (order-invariant adds -> deterministic),
// prefix-scans 320 buckets -> hcm.
// cumsum error <= 32000*2^-20 ~ 0.03, vs ~3.0 step between candidates.
__global__ __launch_bounds__(RT_THREADS) void k3a_rank(
    const unsigned long long* __restrict__ key, unsigned* __restrict__ rankc,
    unsigned long long* __restrict__ aux, int* __restrict__ hcm) {
  __shared__ unsigned long long jk[RT_TJ];
  __shared__ unsigned long long bl[321];
  __shared__ int lastf;
  int g = blockIdx.x / N_JTILE;
  int q = blockIdx.x % N_JTILE;
  int tid = threadIdx.x;
  int j0 = q * RT_TJ;
  for (int j = tid; j < RT_TJ; j += RT_THREADS) jk[j] = key[j0 + j];
  unsigned long long own[RT_OWN];
  int e0 = g * RT_TI + tid;
#pragma unroll
  for (int m = 0; m < RT_OWN; ++m) {
    int e = e0 + m * RT_THREADS;
    own[m] = (e < LL) ? key[e] : ~0ull;
  }
  __syncthreads();
  unsigned cnt[RT_OWN] = {0u, 0u, 0u, 0u};
#pragma unroll 4
  for (int j = 0; j < RT_TJ; ++j) {
    unsigned long long kj = jk[j];
#pragma unroll
    for (int m = 0; m < RT_OWN; ++m) cnt[m] += (kj > own[m]) ? 1u : 0u;
  }
#pragma unroll
  for (int m = 0; m < RT_OWN; ++m) {
    int e = e0 + m * RT_THREADS;
    if (e < LL) atomicAdd(&rankc[e], cnt[m]);
  }
  // last-block-done epilogue (small atomic traffic only -> cheap fence)
  __threadfence();
  __syncthreads();
  if (tid == 0) {
    unsigned long long prev = atomicAdd(&aux[0], 1ull);
    lastf = (prev == (unsigned long long)(RT_NBLK - 1)) ? 1 : 0;
  }
  __syncthreads();
  if (!lastf) return;
  for (int i = tid; i < 321; i += RT_THREADS) bl[i] = 0ull;
  __syncthreads();
  for (int e = tid; e < LL; e += RT_THREADS) {
    unsigned rank = atomicAdd(&rankc[e], 0u);  // device-coherent read
    float p = u2f((unsigned)(key[e] >> 32));
    unsigned long long qv = (unsigned long long)(p * 1048576.0f);
    atomicAdd(&bl[rank / 100u], qv);           // LDS u64 add (deterministic)
    if (rank == 0u) bl[320] = qv;              // single writer
  }
  __syncthreads();
  if (tid == 0) {
    const unsigned long long Rq = 998579896ull;  // floor(0.93*1024*2^20)
    unsigned long long run = 0;
    int hc = -1;
    for (int m = 0; m < 320; ++m) {
      unsigned long long val = (m == 0) ? bl[320] : run;  // cand=1 -> top1
      if (val >= Rq) { hc = m; break; }
      run += bl[m];
    }
    *hcm = (hc < 0) ? 1 : 1 + 100 * hc;  // all-False -> cand[0] = 1
  }
}

// K45: fused per-row exact top-k threshold (LDS u16 cache + 2048/32-bin
// two-level histogram, wave-shfl scans) + stable tie cutoff + masked loss
// sums (branch-free) + ls -> out copy (rides the phase-A read).
// Copy uses NONTEMPORAL stores and lt uses NONTEMPORAL loads: neither is
// ever re-read, so keep L2 reserved for the ls rows phases C/E/G re-read.
__global__ __launch_bounds__(1024) void k45_fused(
    const float* __restrict__ ls, const float* __restrict__ lt,
    const int* __restrict__ tgt, const int* __restrict__ hcm,
    const float* __restrict__ stats, float* __restrict__ outc,
    float* __restrict__ ce_a, float* __restrict__ bin_a,
    float* __restrict__ hd_a) {
  __shared__ unsigned short u16row[LL];   // 64000 B
  __shared__ unsigned hist[2048];         // 8192 B (reused: 32-bin subhist)
  __shared__ unsigned scratch[1024];      // 4096 B (wtot / grp / partials)
  __shared__ int ctl[8];
  __shared__ float sst[8];

  int r = blockIdx.x, tid = threadIdx.x;
  int lane = tid & 63, wv = tid >> 6;
  int t = tgt[r];
  int k = *hcm;
  const float* row_s = ls + (size_t)r * LL;
  const float* row_t = lt + (size_t)r * LL;
  const unsigned U999 = f2u(999999.0f);

  for (int i = tid; i < 2048; i += NT) hist[i] = 0;
  if (tid == 0) { ctl[4] = 0; ctl[5] = 0; ctl[6] = 0; }
  if (tid < 4) sst[tid] = stats[r * 8 + tid];
  __syncthreads();

  // phase A: read ls row -> NT out copy + u16 LDS cache + 2048-bin histogram
  const vfloat4* a4 = (const vfloat4*)row_s;
  vfloat4* o4 = (vfloat4*)(outc + (size_t)r * LL);
  for (int i = tid; i < LL / 4; i += NT) {
    vfloat4 a = a4[i];
    __builtin_nontemporal_store(a, &o4[i]);
    int c0 = 4 * i;
    ushort4 pk;
    unsigned short* pp = (unsigned short*)&pk;
#pragma unroll
    for (int j = 0; j < 4; ++j) {
      unsigned u = f2u(a[j]);
      pp[j] = (unsigned short)(u >> 16);
      atomicAdd(&hist[u >> 21], 1u);
    }
    *(ushort4*)(u16row + c0) = pk;
  }
  __syncthreads();
  if (tid == 0) {  // target fixup: move x_t from its bin to U999's bin
    unsigned uo = f2u(row_s[t]);
    atomicAdd(&hist[uo >> 21], 0xFFFFFFFFu);   // -1
    atomicAdd(&hist[U999 >> 21], 1u);
    u16row[t] = (unsigned short)(U999 >> 16);
  }
  __syncthreads();

  // phase B: wave-shfl suffix scan over 2048 bins (each thread owns 2 bins)
  {
    int* wtot = (int*)scratch;
    int h0 = (int)hist[2 * tid], h1 = (int)hist[2 * tid + 1];
    int s = h0 + h1;
    for (int o = 1; o < 64; o <<= 1) {
      int v = __shfl_down(s, o);
      if (lane + o < 64) s += v;
    }
    if (lane == 0) wtot[wv] = s;
    __syncthreads();
    int sw = 0;
    for (int w2 = wv + 1; w2 < 16; ++w2) sw += wtot[w2];
    int S_pair = s + sw;                 // suffix_incl(2*tid)
    int i1 = S_pair - h0;                // suffix_incl(2*tid+1)
    int i2 = i1 - h1;                    // suffix_incl(2*tid+2)
    if (S_pair >= k && i1 < k) { ctl[0] = 2 * tid; ctl[1] = k - i1; }
    if (i1 >= k && i2 < k) { ctl[0] = 2 * tid + 1; ctl[1] = k - i2; }
  }
  __syncthreads();
  int B11 = ctl[0], r11 = ctl[1];
  if (tid < 32) hist[tid] = 0;
  __syncthreads();

  // phase C: 32-bin low-5-bit subhistogram within bucket B11
  for (int i = tid; i < LL / 4; i += NT) {
    ushort4 kk = *(const ushort4*)(u16row + 4 * i);
    const unsigned short* kp = (const unsigned short*)&kk;
#pragma unroll
    for (int j = 0; j < 4; ++j) {
      unsigned v = kp[j];
      if ((int)(v >> 5) == B11) atomicAdd(&hist[v & 31u], 1u);
    }
  }
  __syncthreads();
  if (wv == 0 && lane < 32) {
    int h = (int)hist[lane];
    int s = h;
    for (int o = 1; o < 32; o <<= 1) {
      int v = __shfl_down(s, o);
      if (lane + o < 32) s += v;
    }
    int nxt = s - h;
    if (s >= r11 && nxt < r11) { ctl[2] = lane; ctl[3] = r11 - nxt; }
  }
  __syncthreads();
  unsigned P16 = ((unsigned)B11 << 5) | (unsigned)ctl[2];
  int rr = ctl[3];

  // phase E: collect the tied-u16 group (full 32-bit keys, ~60 elements)
  unsigned* grp = scratch;
  for (int i = tid; i < LL / 4; i += NT) {
    ushort4 kk = *(const ushort4*)(u16row + 4 * i);
    const unsigned short* kp = (const unsigned short*)&kk;
#pragma unroll
    for (int j = 0; j < 4; ++j) {
      int c = 4 * i + j;
      if ((unsigned)kp[j] == P16) {
        int pos = atomicAdd(&ctl[4], 1);
        if (pos < CAP) {
          float x = (c == t) ? 999999.0f : row_s[c];
          grp[2 * pos] = f2u(x);
          grp[2 * pos + 1] = (unsigned)c;
        }
      }
    }
  }
  __syncthreads();
  int m = ctl[4]; if (m > CAP) m = CAP;

  // phase F: exact rank within group by (u32 desc, col asc); pick rr-th
  for (int gi = tid; gi < m; gi += NT) {
    unsigned ui = grp[2 * gi], ci = grp[2 * gi + 1];
    int rank = 0;
    for (int j = 0; j < m; ++j) {
      unsigned uj = grp[2 * j], cj = grp[2 * j + 1];
      rank += (uj > ui || (uj == ui && cj < ci)) ? 1 : 0;
    }
    if (rank == rr - 1) { ctl[5] = (int)ci; ctl[6] = (int)ui; }
  }
  __syncthreads();
  unsigned thrU = (unsigned)ctl[6];
  int cut = ctl[5];
  unsigned short thr16 = (unsigned short)(thrU >> 16);
  __syncthreads();  // scratch (grp) dead; reused for partials below

  // phase G: masked loss sums; hard-mask from LDS u16 (target-adjusted),
  // slow 32-bit path only for tied-u16 elements; branch-free exps.
  float s1 = sst[0], sT = sst[1], lst = sst[2];
  float a_s = 0.f, tT = 0.f, a_t = 0.f, w = 0.f;
  const vfloat4* b4 = (const vfloat4*)row_t;
  for (int i = tid; i < LL / 4; i += NT) {
    vfloat4 a = a4[i];
    vfloat4 b = __builtin_nontemporal_load(&b4[i]);
    ushort4 kk = *(const ushort4*)(u16row + 4 * i);
    const unsigned short* kp = (const unsigned short*)&kk;
    int c0 = 4 * i;
#pragma unroll
    for (int j = 0; j < 4; ++j) {
      int c = c0 + j;
      float x = a[j], y = b[j];
      unsigned short u16 = kp[j];
      bool hard;
      if (u16 != thr16) {
        hard = (u16 > thr16);
      } else {
        unsigned u = (c == t) ? U999 : f2u(x);
        hard = (u > thrU) || (u == thrU && c <= cut);
      }
      float et = __expf(y * TINV);
      float es = __expf(x * TINV);
      tT += et;
      float h = hard ? 1.f : 0.f;
      a_t += h * et;
      w += h * et * (y - x);
      a_s += h * es;
    }
  }
  for (int o = 32; o > 0; o >>= 1) {
    a_s += __shfl_down(a_s, o);
    tT += __shfl_down(tT, o);
    a_t += __shfl_down(a_t, o);
    w += __shfl_down(w, o);
  }
  float* pf = (float*)scratch;
  if (lane == 0) {
    pf[wv * 4 + 0] = a_s; pf[wv * 4 + 1] = tT;
    pf[wv * 4 + 2] = a_t; pf[wv * 4 + 3] = w;
  }
  __syncthreads();
  if (wv == 0) {
    float aS = 0.f, t2T = 0.f, a2T = 0.f, w2w = 0.f;
    if (lane < 16) {
      aS = pf[lane * 4 + 0]; t2T = pf[lane * 4 + 1];
      a2T = pf[lane * 4 + 2]; w2w = pf[lane * 4 + 3];
    }
    for (int o = 1; o < 16; o <<= 1) {
      float sb = __shfl_down(aS, o);
      float tb = __shfl_down(t2T, o);
      float ab = __shfl_down(a2T, o);
      float wb = __shfl_down(w2w, o);
      if (lane + o < 16) { aS += sb; t2T += tb; a2T += ab; w2w += wb; }
    }
    if (lane == 0) {
      float hs = aS / sT, ht = a2T / t2T;
      float bin = 0.f;
      if (ht > 0.f) bin += ht * (logf(ht) - logf(hs));
      float htn = 1.f - ht, hsn = 1.f - hs;
      if (htn > 0.f) bin += htn * (logf(htn) - logf(hsn));
      float hd = (w2w * TINV) / a2T - logf(a2T) + logf(aS);
      ce_a[r] = logf(s1) - lst;
      bin_a[r] = bin;
      hd_a[r] = hd;
    }
  }
}

// K6: deterministic final reduction + scalars
__global__ __launch_bounds__(256) void k6_final(
    const float* __restrict__ ce_a, const float* __restrict__ bin_a,
    const float* __restrict__ hd_a, const int* __restrict__ epoch,
    float* __restrict__ out2) {
  __shared__ float r1[256], r2[256], r3[256];
  int tid = threadIdx.x;
  float a = 0.f, b = 0.f, c = 0.f;
  for (int i = tid; i < BB; i += 256) { a += ce_a[i]; b += bin_a[i]; c += hd_a[i]; }
  r1[tid] = a; r2[tid] = b; r3[tid] = c;
  __syncthreads();
  for (int o = 128; o > 0; o >>= 1) {
    if (tid < o) { r1[tid] += r1[tid + o]; r2[tid] += r2[tid + o]; r3[tid] += r3[tid + o]; }
    __syncthreads();
  }
  if (tid == 0) {
    float loss_ce = r1[0] / (float)BB;
    float tsq = 16.0f / (float)BB;
    float binary_loss = r2[0] * tsq;
    float hard_loss = r3[0] * tsq;
    float warm = fminf((float)(*epoch) / 10.0f, 1.0f);
    float loss_kd = warm * (1.0f * binary_loss + 4.0f * hard_loss);
    out2[0] = loss_ce;
    out2[1] = loss_kd;
  }
}

extern "C" void kernel_launch(void* const* d_in, const int* in_sizes, int n_in,
                              void* d_out, int out_size, void* d_ws, size_t ws_size,
                              hipStream_t stream) {
  const float* ls = (const float*)d_in[0];
  const float* lt = (const float*)d_in[1];
  const int* tgt = (const int*)d_in[2];
  const int* epoch = (const int*)d_in[3];
  float* out = (float*)d_out;

  char* ws = (char*)d_ws;
  size_t off = 0;
  float* stats = (float*)(ws + off); off += (size_t)BB * 8 * 4;          // 32 KB
  float* part = (float*)(ws + off); off += (size_t)NCHUNK * LL * 4;      // 2 MB
  int* hcm = (int*)(ws + off); off += 256;
  float* ce_a = (float*)(ws + off); off += (size_t)BB * 4;
  float* bin_a = (float*)(ws + off); off += (size_t)BB * 4;
  float* hd_a = (float*)(ws + off); off += (size_t)BB * 4;
  unsigned long long* key = (unsigned long long*)(ws + off); off += (size_t)LL * 8;  // 256 KB
  unsigned long long* aux = (unsigned long long*)(ws + off); off += 256;
  // rankc aliases part: part is dead after k2b (which zeroes rankc
  // column-exclusively); k3a accumulates ranks via integer atomics.
  unsigned* rankc = (unsigned*)part;    // LL * 4 = 128 KB

  hipLaunchKernelGGL(k1_stats, dim3(BB), dim3(256), 0, stream, ls, tgt, stats);
  hipLaunchKernelGGL(k2a_prob_part, dim3(LL / 256, NCHUNK), dim3(256), 0, stream, ls, stats, part, aux);
  hipLaunchKernelGGL(k2b_prob, dim3(LL / 256), dim3(256), 0, stream, part, key, rankc);
  hipLaunchKernelGGL(k3a_rank, dim3(RT_NBLK), dim3(RT_THREADS), 0, stream, key, rankc, aux, hcm);
  hipLaunchKernelGGL(k45_fused, dim3(BB), dim3(NT), 0, stream, ls, lt, tgt, hcm, stats, out, ce_a, bin_a, hd_a);
  hipLaunchKernelGGL(k6_final, dim3(1), dim3(256), 0, stream, ce_a, bin_a, hd_a, epoch, out + (size_t)BB * LL);
}

// Round 12
// 240.334 us; speedup vs baseline: 1.3614x; 1.3614x over previous
//
#include <hip/hip_runtime.h>
#include <hip/hip_bf16.h>
#include <math.h>

#define BB 1024
#define LL 32000
#define NCHUNK 16              // row chunks for prob partial sums
#define ROWS_PER_CHUNK (BB / NCHUNK)
#define NT 1024                // threads per block in fused k45
#define CAP 512                // max tied-u16-prefix group size (expect ~60)

// k3a rank tiling
#define RT_THREADS 256
#define RT_OWN 4                         // own keys per thread (in VGPRs)
#define RT_TI (RT_THREADS * RT_OWN)      // 1024 own elements per block
#define RT_TJ 500                        // j-tile size (4 KB LDS)
#define N_JTILE (LL / RT_TJ)             // 64
#define NPAD 32768
#define N_OWN_GRP (NPAD / RT_TI)         // 32
#define RT_NBLK (N_OWN_GRP * N_JTILE)    // 2048

// aux layout (u64 slots): [0..319] rank buckets, [320] top1 value,
// [321] k3bc done counter
#define AUX_SLOTS 322

constexpr float TINV = 0.25f;  // 1/T, T=4

// NOTE: all exponentials are computed WITHOUT max-stabilization. Inputs are
// N(0,1) logits (|x| < ~6), so e^x <= ~e^6 and e^{x/4} <= e^1.5 — no overflow
// or underflow risk in f32, and sums (<= ~5.3e4) are well within range.
//
// FENCE RULE (learned rounds 9 & 11): never put __threadfence() in a kernel
// whose blocks carry a live store/atomic stream (1024-2048 fences cost
// 50-100 us by forcing XCD-L2 drains). Fences only in tiny-grid kernels
// (k3bc: 125 blocks, measured ~4 us).

typedef float vfloat4 __attribute__((ext_vector_type(4)));

__device__ __forceinline__ unsigned f2u(float x) {
  unsigned b = __float_as_uint(x);
  return (b & 0x80000000u) ? ~b : (b | 0x80000000u);
}
__device__ __forceinline__ float u2f(unsigned u) {
  unsigned b = (u & 0x80000000u) ? (u ^ 0x80000000u) : ~u;
  return __uint_as_float(b);
}

// K1: per-row student sums (branch-free). Pure 128 MB read-reduce.
__global__ __launch_bounds__(256) void k1_stats(
    const float* __restrict__ ls, const int* __restrict__ tgt,
    float* __restrict__ stats) {
  int r = blockIdx.x, tid = threadIdx.x;
  int lane = tid & 63, wv = tid >> 6;
  const float4* a4 = (const float4*)(ls + (size_t)r * LL);
  float s1 = 0.f, sT = 0.f;
  for (int i = tid; i < LL / 4; i += 256) {
    float4 a = a4[i];
    s1 += __expf(a.x) + __expf(a.y) + __expf(a.z) + __expf(a.w);
    sT += __expf(a.x * TINV) + __expf(a.y * TINV) +
          __expf(a.z * TINV) + __expf(a.w * TINV);
  }
  for (int o = 32; o > 0; o >>= 1) {
    s1 += __shfl_down(s1, o);
    sT += __shfl_down(sT, o);
  }
  __shared__ float wsum[8];
  if (lane == 0) { wsum[wv * 2] = s1; wsum[wv * 2 + 1] = sT; }
  __syncthreads();
  if (tid == 0) {
    float t1 = wsum[0] + wsum[2] + wsum[4] + wsum[6];
    float tT = wsum[1] + wsum[3] + wsum[5] + wsum[7];
    float lst = ls[(size_t)r * LL + tgt[r]];
    float* st = stats + r * 8;
    st[0] = t1; st[1] = tT; st[2] = lst; st[3] = 1.0f / t1;
  }
}

// K2a: partial column sums of T=1 softmax. Block (0,0) also zeroes the aux
// counters/buckets for this call (consumed by later kernels only).
__global__ __launch_bounds__(256) void k2a_prob_part(
    const float* __restrict__ ls, const float* __restrict__ stats,
    float* __restrict__ part, unsigned long long* __restrict__ aux) {
  if (blockIdx.x == 0 && blockIdx.y == 0) {
    for (int i = threadIdx.x; i < AUX_SLOTS; i += 256) aux[i] = 0ull;
  }
  int c = blockIdx.x * 256 + threadIdx.x;
  int r0 = blockIdx.y * ROWS_PER_CHUNK;
  float acc = 0.f;
#pragma unroll 8
  for (int rr = 0; rr < ROWS_PER_CHUNK; ++rr) {
    int r = r0 + rr;
    float rs = stats[r * 8 + 3];
    acc += __expf(ls[(size_t)r * LL + c]) * rs;
  }
  part[(size_t)blockIdx.y * LL + c] = acc;
}

// K2b: combine partials (deterministic) -> strict-total-order sort keys
// + zero the rank accumulator (aliased on part: column-exclusive, race-free).
__global__ __launch_bounds__(256) void k2b_prob(
    const float* __restrict__ part, unsigned long long* __restrict__ key,
    unsigned* __restrict__ rankc) {
  int c = blockIdx.x * 256 + threadIdx.x;
  float acc = 0.f;
#pragma unroll
  for (int j = 0; j < NCHUNK; ++j) acc += part[(size_t)j * LL + c];
  key[c] = ((unsigned long long)f2u(acc) << 32) | (unsigned)c;
  rankc[c] = 0u;
}

// K3a: tiled rank-by-counting; deterministic integer atomics into rankc.
// NO fences, no epilogue (round-11 lesson).
__global__ __launch_bounds__(RT_THREADS) void k3a_rank(
    const unsigned long long* __restrict__ key, unsigned* __restrict__ rankc) {
  __shared__ unsigned long long jk[RT_TJ];
  int g = blockIdx.x / N_JTILE;
  int q = blockIdx.x % N_JTILE;
  int tid = threadIdx.x;
  int j0 = q * RT_TJ;
  for (int j = tid; j < RT_TJ; j += RT_THREADS) jk[j] = key[j0 + j];
  unsigned long long own[RT_OWN];
  int e0 = g * RT_TI + tid;
#pragma unroll
  for (int m = 0; m < RT_OWN; ++m) {
    int e = e0 + m * RT_THREADS;
    own[m] = (e < LL) ? key[e] : ~0ull;
  }
  __syncthreads();
  unsigned cnt[RT_OWN] = {0u, 0u, 0u, 0u};
#pragma unroll 4
  for (int j = 0; j < RT_TJ; ++j) {
    unsigned long long kj = jk[j];
#pragma unroll
    for (int m = 0; m < RT_OWN; ++m) cnt[m] += (kj > own[m]) ? 1u : 0u;
  }
#pragma unroll
  for (int m = 0; m < RT_OWN; ++m) {
    int e = e0 + m * RT_THREADS;
    if (e < LL) atomicAdd(&rankc[e], cnt[m]);
  }
}

// K3bc: bucket quantized probs by rank/100 (deterministic u64 fixed-point
// atomics, scale 2^20), capture the rank-0 value for cand=1, then the LAST
// block (device-scope counter; only 125 blocks -> fence is cheap) prefix-
// scans 320 buckets -> hcm.
// cumsum error <= 32000*2^-20 ~ 0.03, vs ~3.0 step between candidates.
__global__ __launch_bounds__(256) void k3bc_select(
    const unsigned* __restrict__ rankc, const unsigned long long* __restrict__ key,
    unsigned long long* __restrict__ aux, int* __restrict__ hcm) {
  __shared__ unsigned long long bl[321];
  __shared__ int lastf;
  int tid = threadIdx.x;
  int e = blockIdx.x * 256 + tid;
  unsigned rank = rankc[e];
  float p = u2f((unsigned)(key[e] >> 32));
  unsigned long long q = (unsigned long long)(p * 1048576.0f);
  atomicAdd(&aux[rank / 100u], q);
  if (rank == 0u) atomicExch(&aux[320], q);
  __threadfence();
  __syncthreads();
  if (tid == 0) {
    unsigned long long prev = atomicAdd(&aux[321], 1ull);
    lastf = (prev == (unsigned long long)(LL / 256 - 1)) ? 1 : 0;
  }
  __syncthreads();
  if (!lastf) return;
  for (int i = tid; i < 321; i += 256) bl[i] = atomicAdd(&aux[i], 0ull);
  __syncthreads();
  if (tid == 0) {
    const unsigned long long Rq = 998579896ull;  // floor(0.93*1024*2^20)
    unsigned long long run = 0;
    int hc = -1;
    for (int m = 0; m < 320; ++m) {
      unsigned long long val = (m == 0) ? bl[320] : run;  // cand=1 -> top1
      if (val >= Rq) { hc = m; break; }
      run += bl[m];
    }
    *hcm = (hc < 0) ? 1 : 1 + 100 * hc;  // all-False -> cand[0] = 1
  }
}

// K45: fused per-row exact top-k threshold (LDS u16 cache + 2048/32-bin
// two-level histogram, wave-shfl scans) + stable tie cutoff + masked loss
// sums (branch-free) + ls -> out copy (rides the phase-A read).
// Copy uses NONTEMPORAL stores and lt uses NONTEMPORAL loads: neither is
// ever re-read, so keep L2 reserved for the ls rows phases C/E/G re-read.
__global__ __launch_bounds__(1024) void k45_fused(
    const float* __restrict__ ls, const float* __restrict__ lt,
    const int* __restrict__ tgt, const int* __restrict__ hcm,
    const float* __restrict__ stats, float* __restrict__ outc,
    float* __restrict__ ce_a, float* __restrict__ bin_a,
    float* __restrict__ hd_a) {
  __shared__ unsigned short u16row[LL];   // 64000 B
  __shared__ unsigned hist[2048];         // 8192 B (reused: 32-bin subhist)
  __shared__ unsigned scratch[1024];      // 4096 B (wtot / grp / partials)
  __shared__ int ctl[8];
  __shared__ float sst[8];

  int r = blockIdx.x, tid = threadIdx.x;
  int lane = tid & 63, wv = tid >> 6;
  int t = tgt[r];
  int k = *hcm;
  const float* row_s = ls + (size_t)r * LL;
  const float* row_t = lt + (size_t)r * LL;
  const unsigned U999 = f2u(999999.0f);

  for (int i = tid; i < 2048; i += NT) hist[i] = 0;
  if (tid == 0) { ctl[4] = 0; ctl[5] = 0; ctl[6] = 0; }
  if (tid < 4) sst[tid] = stats[r * 8 + tid];
  __syncthreads();

  // phase A: read ls row -> NT out copy + u16 LDS cache + 2048-bin histogram
  const vfloat4* a4 = (const vfloat4*)row_s;
  vfloat4* o4 = (vfloat4*)(outc + (size_t)r * LL);
  for (int i = tid; i < LL / 4; i += NT) {
    vfloat4 a = a4[i];
    __builtin_nontemporal_store(a, &o4[i]);
    int c0 = 4 * i;
    ushort4 pk;
    unsigned short* pp = (unsigned short*)&pk;
#pragma unroll
    for (int j = 0; j < 4; ++j) {
      unsigned u = f2u(a[j]);
      pp[j] = (unsigned short)(u >> 16);
      atomicAdd(&hist[u >> 21], 1u);
    }
    *(ushort4*)(u16row + c0) = pk;
  }
  __syncthreads();
  if (tid == 0) {  // target fixup: move x_t from its bin to U999's bin
    unsigned uo = f2u(row_s[t]);
    atomicAdd(&hist[uo >> 21], 0xFFFFFFFFu);   // -1
    atomicAdd(&hist[U999 >> 21], 1u);
    u16row[t] = (unsigned short)(U999 >> 16);
  }
  __syncthreads();

  // phase B: wave-shfl suffix scan over 2048 bins (each thread owns 2 bins)
  {
    int* wtot = (int*)scratch;
    int h0 = (int)hist[2 * tid], h1 = (int)hist[2 * tid + 1];
    int s = h0 + h1;
    for (int o = 1; o < 64; o <<= 1) {
      int v = __shfl_down(s, o);
      if (lane + o < 64) s += v;
    }
    if (lane == 0) wtot[wv] = s;
    __syncthreads();
    int sw = 0;
    for (int w2 = wv + 1; w2 < 16; ++w2) sw += wtot[w2];
    int S_pair = s + sw;                 // suffix_incl(2*tid)
    int i1 = S_pair - h0;                // suffix_incl(2*tid+1)
    int i2 = i1 - h1;                    // suffix_incl(2*tid+2)
    if (S_pair >= k && i1 < k) { ctl[0] = 2 * tid; ctl[1] = k - i1; }
    if (i1 >= k && i2 < k) { ctl[0] = 2 * tid + 1; ctl[1] = k - i2; }
  }
  __syncthreads();
  int B11 = ctl[0], r11 = ctl[1];
  if (tid < 32) hist[tid] = 0;
  __syncthreads();

  // phase C: 32-bin low-5-bit subhistogram within bucket B11
  for (int i = tid; i < LL / 4; i += NT) {
    ushort4 kk = *(const ushort4*)(u16row + 4 * i);
    const unsigned short* kp = (const unsigned short*)&kk;
#pragma unroll
    for (int j = 0; j < 4; ++j) {
      unsigned v = kp[j];
      if ((int)(v >> 5) == B11) atomicAdd(&hist[v & 31u], 1u);
    }
  }
  __syncthreads();
  if (wv == 0 && lane < 32) {
    int h = (int)hist[lane];
    int s = h;
    for (int o = 1; o < 32; o <<= 1) {
      int v = __shfl_down(s, o);
      if (lane + o < 32) s += v;
    }
    int nxt = s - h;
    if (s >= r11 && nxt < r11) { ctl[2] = lane; ctl[3] = r11 - nxt; }
  }
  __syncthreads();
  unsigned P16 = ((unsigned)B11 << 5) | (unsigned)ctl[2];
  int rr = ctl[3];

  // phase E: collect the tied-u16 group (full 32-bit keys, ~60 elements)
  unsigned* grp = scratch;
  for (int i = tid; i < LL / 4; i += NT) {
    ushort4 kk = *(const ushort4*)(u16row + 4 * i);
    const unsigned short* kp = (const unsigned short*)&kk;
#pragma unroll
    for (int j = 0; j < 4; ++j) {
      int c = 4 * i + j;
      if ((unsigned)kp[j] == P16) {
        int pos = atomicAdd(&ctl[4], 1);
        if (pos < CAP) {
          float x = (c == t) ? 999999.0f : row_s[c];
          grp[2 * pos] = f2u(x);
          grp[2 * pos + 1] = (unsigned)c;
        }
      }
    }
  }
  __syncthreads();
  int m = ctl[4]; if (m > CAP) m = CAP;

  // phase F: exact rank within group by (u32 desc, col asc); pick rr-th
  for (int gi = tid; gi < m; gi += NT) {
    unsigned ui = grp[2 * gi], ci = grp[2 * gi + 1];
    int rank = 0;
    for (int j = 0; j < m; ++j) {
      unsigned uj = grp[2 * j], cj = grp[2 * j + 1];
      rank += (uj > ui || (uj == ui && cj < ci)) ? 1 : 0;
    }
    if (rank == rr - 1) { ctl[5] = (int)ci; ctl[6] = (int)ui; }
  }
  __syncthreads();
  unsigned thrU = (unsigned)ctl[6];
  int cut = ctl[5];
  unsigned short thr16 = (unsigned short)(thrU >> 16);
  __syncthreads();  // scratch (grp) dead; reused for partials below

  // phase G: masked loss sums; hard-mask from LDS u16 (target-adjusted),
  // slow 32-bit path only for tied-u16 elements; branch-free exps.
  float s1 = sst[0], sT = sst[1], lst = sst[2];
  float a_s = 0.f, tT = 0.f, a_t = 0.f, w = 0.f;
  const vfloat4* b4 = (const vfloat4*)row_t;
  for (int i = tid; i < LL / 4; i += NT) {
    vfloat4 a = a4[i];
    vfloat4 b = __builtin_nontemporal_load(&b4[i]);
    ushort4 kk = *(const ushort4*)(u16row + 4 * i);
    const unsigned short* kp = (const unsigned short*)&kk;
    int c0 = 4 * i;
#pragma unroll
    for (int j = 0; j < 4; ++j) {
      int c = c0 + j;
      float x = a[j], y = b[j];
      unsigned short u16 = kp[j];
      bool hard;
      if (u16 != thr16) {
        hard = (u16 > thr16);
      } else {
        unsigned u = (c == t) ? U999 : f2u(x);
        hard = (u > thrU) || (u == thrU && c <= cut);
      }
      float et = __expf(y * TINV);
      float es = __expf(x * TINV);
      tT += et;
      float h = hard ? 1.f : 0.f;
      a_t += h * et;
      w += h * et * (y - x);
      a_s += h * es;
    }
  }
  for (int o = 32; o > 0; o >>= 1) {
    a_s += __shfl_down(a_s, o);
    tT += __shfl_down(tT, o);
    a_t += __shfl_down(a_t, o);
    w += __shfl_down(w, o);
  }
  float* pf = (float*)scratch;
  if (lane == 0) {
    pf[wv * 4 + 0] = a_s; pf[wv * 4 + 1] = tT;
    pf[wv * 4 + 2] = a_t; pf[wv * 4 + 3] = w;
  }
  __syncthreads();
  if (wv == 0) {
    float aS = 0.f, t2T = 0.f, a2T = 0.f, w2w = 0.f;
    if (lane < 16) {
      aS = pf[lane * 4 + 0]; t2T = pf[lane * 4 + 1];
      a2T = pf[lane * 4 + 2]; w2w = pf[lane * 4 + 3];
    }
    for (int o = 1; o < 16; o <<= 1) {
      float sb = __shfl_down(aS, o);
      float tb = __shfl_down(t2T, o);
      float ab = __shfl_down(a2T, o);
      float wb = __shfl_down(w2w, o);
      if (lane + o < 16) { aS += sb; t2T += tb; a2T += ab; w2w += wb; }
    }
    if (lane == 0) {
      float hs = aS / sT, ht = a2T / t2T;
      float bin = 0.f;
      if (ht > 0.f) bin += ht * (logf(ht) - logf(hs));
      float htn = 1.f - ht, hsn = 1.f - hs;
      if (htn > 0.f) bin += htn * (logf(htn) - logf(hsn));
      float hd = (w2w * TINV) / a2T - logf(a2T) + logf(aS);
      ce_a[r] = logf(s1) - lst;
      bin_a[r] = bin;
      hd_a[r] = hd;
    }
  }
}

// K6: deterministic final reduction + scalars
__global__ __launch_bounds__(256) void k6_final(
    const float* __restrict__ ce_a, const float* __restrict__ bin_a,
    const float* __restrict__ hd_a, const int* __restrict__ epoch,
    float* __restrict__ out2) {
  __shared__ float r1[256], r2[256], r3[256];
  int tid = threadIdx.x;
  float a = 0.f, b = 0.f, c = 0.f;
  for (int i = tid; i < BB; i += 256) { a += ce_a[i]; b += bin_a[i]; c += hd_a[i]; }
  r1[tid] = a; r2[tid] = b; r3[tid] = c;
  __syncthreads();
  for (int o = 128; o > 0; o >>= 1) {
    if (tid < o) { r1[tid] += r1[tid + o]; r2[tid] += r2[tid + o]; r3[tid] += r3[tid + o]; }
    __syncthreads();
  }
  if (tid == 0) {
    float loss_ce = r1[0] / (float)BB;
    float tsq = 16.0f / (float)BB;
    float binary_loss = r2[0] * tsq;
    float hard_loss = r3[0] * tsq;
    float warm = fminf((float)(*epoch) / 10.0f, 1.0f);
    float loss_kd = warm * (1.0f * binary_loss + 4.0f * hard_loss);
    out2[0] = loss_ce;
    out2[1] = loss_kd;
  }
}

extern "C" void kernel_launch(void* const* d_in, const int* in_sizes, int n_in,
                              void* d_out, int out_size, void* d_ws, size_t ws_size,
                              hipStream_t stream) {
  const float* ls = (const float*)d_in[0];
  const float* lt = (const float*)d_in[1];
  const int* tgt = (const int*)d_in[2];
  const int* epoch = (const int*)d_in[3];
  float* out = (float*)d_out;

  char* ws = (char*)d_ws;
  size_t off = 0;
  float* stats = (float*)(ws + off); off += (size_t)BB * 8 * 4;          // 32 KB
  float* part = (float*)(ws + off); off += (size_t)NCHUNK * LL * 4;      // 2 MB
  int* hcm = (int*)(ws + off); off += 256;
  float* ce_a = (float*)(ws + off); off += (size_t)BB * 4;
  float* bin_a = (float*)(ws + off); off += (size_t)BB * 4;
  float* hd_a = (float*)(ws + off); off += (size_t)BB * 4;
  unsigned long long* key = (unsigned long long*)(ws + off); off += (size_t)LL * 8;  // 256 KB
  unsigned long long* aux = (unsigned long long*)(ws + off); off += (size_t)AUX_SLOTS * 8;
  // rankc aliases part: part is dead after k2b (which zeroes rankc
  // column-exclusively); k3a accumulates ranks via integer atomics.
  unsigned* rankc = (unsigned*)part;    // LL * 4 = 128 KB

  hipLaunchKernelGGL(k1_stats, dim3(BB), dim3(256), 0, stream, ls, tgt, stats);
  hipLaunchKernelGGL(k2a_prob_part, dim3(LL / 256, NCHUNK), dim3(256), 0, stream, ls, stats, part, aux);
  hipLaunchKernelGGL(k2b_prob, dim3(LL / 256), dim3(256), 0, stream, part, key, rankc);
  hipLaunchKernelGGL(k3a_rank, dim3(RT_NBLK), dim3(RT_THREADS), 0, stream, key, rankc);
  hipLaunchKernelGGL(k3bc_select, dim3(LL / 256), dim3(256), 0, stream, rankc, key, aux, hcm);
  hipLaunchKernelGGL(k45_fused, dim3(BB), dim3(NT), 0, stream, ls, lt, tgt, hcm, stats, out, ce_a, bin_a, hd_a);
  hipLaunchKernelGGL(k6_final, dim3(1), dim3(256), 0, stream, ce_a, bin_a, hd_a, epoch, out + (size_t)BB * LL);
}